// Round 6
// baseline (248.668 us; speedup 1.0000x reference)
//
#include <hip/hip_runtime.h>
#include <math.h>

#define H_IMG 2160
#define W_IMG 3840
#define SPAN 120          // output cols per strip (x0+1 .. x0+120; strip 0 also owns col 0)
#define NSX 32            // 32 * 120 = 3840 exactly; wave covers 128 cols
#define HS 10             // output rows per wave (12 steps = 2 sextets of the period-6 pipeline)
#define WPB 4             // waves per block: block covers 40 rows
#define NSY 54            // 54 * 40 = 2160 exactly
#define NBLOCKS (NSX * NSY)   // 1728
#define NBINS 2048

// MLP x TLP combined: 2-col/lane (64-VGPR, 8-wave/SIMD regime) + ring-pipelined
// loads (depth ring-3, rgb/mask even/odd sets; issue lead >= 2 bodies).
// HISTORY of nulls, all 74-81us: R0 4col rolling (occ 25), R3 4col 2-deep
// (occ 16), R4 4col 4-deep (occ 17), R5 2col rolling (occ 40, BW 1.84TB/s).
// Diagnosis: stall/body ~3000cy (queueing), and in-flight bytes per SIMD =
// waves x loads-in-flight-per-wave never exceeded ~6-8 body-loads: R5 had the
// waves but drained vmcnt every body (rolling copies of in-flight regs);
// R3/R4 had the pipeline but ~3 waves/SIMD. This kernel is the untried cell:
// BOTH. Loads land directly in the registers their consumer (2-3 bodies later)
// reads -- no copies of in-flight values, no per-body drain -- at <=64 VGPRs.
// TRIPWIRE: if VGPR>64 or WRITE_SIZE >> 100KB (spill), state didn't fit.
__global__ __launch_bounds__(256, 4) void shading_main(
    const float* __restrict__ depth,
    const float* __restrict__ rgb,
    const int*   __restrict__ mask,
    const float* __restrict__ lmat,   // [9][3]
    const float* __restrict__ K,      // [3][3]
    float* __restrict__ accum,        // partial {S,C} pairs
    int direct)
{
    const int tid  = threadIdx.x;
    const int lane = tid & 63;
    const int wv   = tid >> 6;
    const int sx   = blockIdx.x;
    const int x0   = sx * SPAN;                    // multiple of 2
    const int y0   = blockIdx.y * (WPB * HS) + wv * HS;
    const int colBase  = x0 + 2 * lane;            // 8B-aligned
    const int colBase3 = 3 * colBase;
    const bool fullIn = (colBase + 1) < W_IMG;     // 2-col groups: fully in or out

    // ---- Kinv (adjugate/det; uniform -> SGPRs) ----
    const float m00 = K[0], m01 = K[1], m02 = K[2];
    const float m10 = K[3], m11 = K[4], m12 = K[5];
    const float m20 = K[6], m21 = K[7], m22 = K[8];
    const float det = m00*(m11*m22 - m12*m21)
                    - m01*(m10*m22 - m12*m20)
                    + m02*(m10*m21 - m11*m20);
    const float id  = 1.0f / det;
    const float i00 = (m11*m22 - m12*m21) * id;
    const float i01 = (m02*m21 - m01*m22) * id;
    const float i02 = (m01*m12 - m02*m11) * id;
    const float i10 = (m12*m20 - m10*m22) * id;
    const float i11 = (m00*m22 - m02*m20) * id;
    const float i12 = (m02*m10 - m00*m12) * id;
    const float i20 = (m10*m21 - m11*m20) * id;
    const float i21 = (m01*m20 - m00*m21) * id;
    const float i22 = (m00*m11 - m01*m10) * id;

    float L[27];
    #pragma unroll
    for (int i = 0; i < 27; ++i) L[i] = lmat[i];   // uniform -> s_load

    // ---- output ownership: strip owns lc in [1,120] (strip 0 also lc=0) ----
    float wout[2];
    #pragma unroll
    for (int k = 0; k < 2; ++k) {
        const int c  = colBase + k;
        const int lc = 2 * lane + k;
        const bool v = (c < W_IMG) && (lc <= SPAN) && (lc >= 1 || sx == 0);
        wout[k] = v ? 1.0f : 0.0f;
    }
    const float qm1s = (lane == 0) ? 0.0f : 1.0f;  // zero-pad left edge (strip 0)

    // ---- ray at (colBase, y0-1); +Kinv col1 per row ----
    float rx = fmaf(i00, (float)colBase, fmaf(i01, (float)(y0 - 1), i02));
    float ry = fmaf(i10, (float)colBase, fmaf(i11, (float)(y0 - 1), i12));
    float rz = fmaf(i20, (float)colBase, fmaf(i21, (float)(y0 - 1), i22));

    const float2 Z2 = make_float2(0.f, 0.f);

    // ---- load-destination registers ----
    // depth ring-3: body j uses (d[j%3]=row h, d[(j+1)%3]=row h+1), issues
    // row h+3 into d[j%3] (next read: 2 bodies later as DNXT, 3 as DCUR).
    float2 d0 = Z2, d1 = Z2, d2 = Z2;
    // rgb/mask parity sets: body j (even/odd) reads its set (row h), issues
    // row h+2 into the same set (read 2 bodies later).
    float2 raE = Z2, rbE = Z2, rcE = Z2;  int2 mE = make_int2(0, 0);
    float2 raO = Z2, rbO = Z2, rcO = Z2;  int2 mO = make_int2(0, 0);

    // ---- prologue: d0..d2 = depth(y0-1..y0+1); E = rgb/mask(y0-1); O = (y0) ----
    // (y0+1 <= 2151 < H always: NSY tiles 2160 exactly)
    if (fullIn) {
        if (y0 > 0) {
            const size_t r = (size_t)(y0 - 1);
            d0  = *(const float2*)(depth + r * W_IMG + colBase);
            raE = *(const float2*)(rgb + r * (3 * W_IMG) + colBase3);
            rbE = *(const float2*)(rgb + r * (3 * W_IMG) + colBase3 + 2);
            rcE = *(const float2*)(rgb + r * (3 * W_IMG) + colBase3 + 4);
            mE  = *(const int2*)(mask + r * W_IMG + colBase);
        }
        {
            const size_t r = (size_t)y0;
            d1  = *(const float2*)(depth + r * W_IMG + colBase);
            raO = *(const float2*)(rgb + r * (3 * W_IMG) + colBase3);
            rbO = *(const float2*)(rgb + r * (3 * W_IMG) + colBase3 + 2);
            rcO = *(const float2*)(rgb + r * (3 * W_IMG) + colBase3 + 4);
            mO  = *(const int2*)(mask + r * W_IMG + colBase);
        }
        d2 = *(const float2*)(depth + (size_t)(y0 + 1) * W_IMG + colBase);
    }

    // rolling arithmetic rings (ALU values -- rotation copies are harmless;
    // only LOAD destinations must never be copied while in flight)
    float sA0[2] = {0,0}, sA1[2] = {0,0}, sA2[2] = {0,0};
    float sB0[2] = {0,0}, sB1[2] = {0,0}, sB2[2] = {0,0};
    float qB0[2] = {0,0}, qB1[2] = {0,0}, qB2[2] = {0,0};
    float wB[2]  = {0,0};
    float accS = 0.f, accC = 0.f;

// One body: snapshot operands, IMMEDIATELY issue replacement loads (depth row
// HD -> DC slot; rgb/mask row HR -> own parity set), shade row h, horizontal
// 3-tap, emit row h-1 (if EM), rotate s/q/w rings.
#define BODY(DC, DN, RA, RB, RC, MM, HD, HR, EM) do {                          \
    const float dc0 = DC.x, dc1 = DC.y;                                        \
    const float dn0 = DN.x, dn1 = DN.y;                                        \
    const float rr0 = RA.x, rr1 = RA.y, rr2 = RB.x;                            \
    const float rr3 = RB.y, rr4 = RC.x, rr5 = RC.y;                            \
    const int   mm0 = MM.x, mm1 = MM.y;                                        \
    const float dcR = __shfl_down(DC.x, 1, 64);                                \
    /* issue replacement loads first: max lead */                              \
    {                                                                          \
        const int hD = (HD);                                                   \
        DC = Z2;                                                               \
        if (fullIn && hD < H_IMG)                                              \
            DC = *(const float2*)(depth + (size_t)hD * W_IMG + colBase);       \
        const int hR = (HR);                                                   \
        RA = Z2; RB = Z2; RC = Z2; MM = make_int2(0, 0);                       \
        if (fullIn && hR < H_IMG) {                                            \
            const float* rr = rgb + (size_t)hR * (3 * W_IMG);                  \
            RA = *(const float2*)(rr + colBase3);                              \
            RB = *(const float2*)(rr + colBase3 + 2);                          \
            RC = *(const float2*)(rr + colBase3 + 4);                          \
            MM = *(const int2*)(mask + (size_t)hR * W_IMG + colBase);          \
        }                                                                      \
    }                                                                          \
    float qC0[2], qC1[2], qC2[2], wC[2];                                       \
    {                                                                          \
        const float dcv[2] = {dc0, dc1};                                       \
        const float dnv[2] = {dn0, dn1};                                       \
        const float rrv[6] = {rr0, rr1, rr2, rr3, rr4, rr5};                   \
        const int   mmv[2] = {mm0, mm1};                                       \
        float rxk = rx, ryk = ry, rzk = rz;                                    \
        _Pragma("unroll")                                                      \
        for (int k = 0; k < 2; ++k) {                                          \
            const float dd0 = dcv[k];                                          \
            const float dR = (k == 0) ? dcv[1] : dcR;                          \
            const float dD = dnv[k];                                           \
            const float px = rxk * dd0, py = ryk * dd0, pz = rzk * dd0;        \
            const float ax = (rxk + i00) * dR - px;                            \
            const float ay = (ryk + i10) * dR - py;                            \
            const float az = (rzk + i20) * dR - pz;                            \
            const float bx = (rxk + i01) * dD - px;                            \
            const float by = (ryk + i11) * dD - py;                            \
            const float bz = (rzk + i21) * dD - pz;                            \
            float nx = ay*bz - az*by;                                          \
            float ny = az*bx - ax*bz;                                          \
            float nz = ax*by - ay*bx;                                          \
            const float nn  = nx*nx + ny*ny + nz*nz;                           \
            const float inr = __builtin_amdgcn_rsqf(fmaxf(nn, 1e-24f));        \
            nx *= inr; ny *= inr; nz *= inr;                                   \
            const float h4 = nx*ny, h5 = ny*nz, h7 = nz*nx;                    \
            const float nx2 = nx*nx, ny2 = ny*ny, nz2 = nz*nz;                 \
            const float h6 = 2.f*nz2 - nx2 - ny2;                              \
            const float h8 = nx2 - ny2;                                        \
            const float B0 = L[0] + ny*L[3] + nz*L[6] + nx*L[9]  + h4*L[12]    \
                           + h5*L[15] + h6*L[18] + h7*L[21] + h8*L[24];        \
            const float B1 = L[1] + ny*L[4] + nz*L[7] + nx*L[10] + h4*L[13]    \
                           + h5*L[16] + h6*L[19] + h7*L[22] + h8*L[25];        \
            const float B2 = L[2] + ny*L[5] + nz*L[8] + nx*L[11] + h4*L[14]    \
                           + h5*L[17] + h6*L[20] + h7*L[23] + h8*L[26];        \
            const float m  = (mmv[k] > 0) ? 1.0f : 0.0f;                       \
            qC0[k] = fmaf(m, B0, -rrv[3*k + 0]);                               \
            qC1[k] = fmaf(m, B1, -rrv[3*k + 1]);                               \
            qC2[k] = fmaf(m, B2, -rrv[3*k + 2]);                               \
            wC[k]  = m * wout[k];                                              \
            rxk += i00; ryk += i10; rzk += i20;                                \
        }                                                                      \
    }                                                                          \
    /* horizontal 3-tap sums via shuffles (2 px/lane) */                       \
    float sC0[2], sC1[2], sC2[2];                                              \
    {                                                                          \
        const float a0 = __shfl_up(qC0[1], 1, 64) * qm1s;                      \
        const float a1 = __shfl_up(qC1[1], 1, 64) * qm1s;                      \
        const float a2 = __shfl_up(qC2[1], 1, 64) * qm1s;                      \
        const float p0 = __shfl_down(qC0[0], 1, 64);                           \
        const float p1 = __shfl_down(qC1[0], 1, 64);                           \
        const float p2 = __shfl_down(qC2[0], 1, 64);                           \
        const float t0 = qC0[0] + qC0[1];                                      \
        sC0[0] = a0 + t0;  sC0[1] = t0 + p0;                                   \
        const float t1 = qC1[0] + qC1[1];                                      \
        sC1[0] = a1 + t1;  sC1[1] = t1 + p1;                                   \
        const float t2 = qC2[0] + qC2[1];                                      \
        sC2[0] = a2 + t2;  sC2[1] = t2 + p2;                                   \
    }                                                                          \
    /* emit row h-1: diff = q - sum3x3/9 */                                    \
    if (EM) {                                                                  \
        _Pragma("unroll")                                                      \
        for (int k = 0; k < 2; ++k) {                                          \
            const float v0 = sA0[k] + sB0[k] + sC0[k];                         \
            const float v1 = sA1[k] + sB1[k] + sC1[k];                         \
            const float v2 = sA2[k] + sB2[k] + sC2[k];                         \
            const float e0 = fmaf(v0, -(1.f/9.f), qB0[k]);                     \
            const float e1 = fmaf(v1, -(1.f/9.f), qB1[k]);                     \
            const float e2 = fmaf(v2, -(1.f/9.f), qB2[k]);                     \
            const float w  = wB[k];                                            \
            accS = fmaf(w, e0*e0 + e1*e1 + e2*e2, accS);                       \
            accC += w;                                                         \
        }                                                                      \
    }                                                                          \
    _Pragma("unroll")                                                          \
    for (int k = 0; k < 2; ++k) {                                              \
        sA0[k] = sB0[k]; sA1[k] = sB1[k]; sA2[k] = sB2[k];                     \
        sB0[k] = sC0[k]; sB1[k] = sC1[k]; sB2[k] = sC2[k];                     \
        qB0[k] = qC0[k]; qB1[k] = qC1[k]; qB2[k] = qC2[k];                     \
        wB[k]  = wC[k];                                                        \
    }                                                                          \
    rx += i01; ry += i11; rz += i21;                                           \
} while (0)

    int hb = y0 - 1;                      // row shaded by body 0 of current sextet
    #pragma unroll 1
    for (int t = 0; t < (HS + 2) / 6; ++t) {
        const bool em = (t >= 1);
        // body j=6t+b shades row hb+b; depth slots (j%3,(j+1)%3); rgb parity j&1
        BODY(d0, d1, raE, rbE, rcE, mE, hb + 3, hb + 2, em);    // b=0
        BODY(d1, d2, raO, rbO, rcO, mO, hb + 4, hb + 3, em);    // b=1
        BODY(d2, d0, raE, rbE, rcE, mE, hb + 5, hb + 4, true);  // b=2
        BODY(d0, d1, raO, rbO, rcO, mO, hb + 6, hb + 5, true);  // b=3
        BODY(d1, d2, raE, rbE, rcE, mE, hb + 7, hb + 6, true);  // b=4
        BODY(d2, d0, raO, rbO, rcO, mO, hb + 8, hb + 7, true);  // b=5
        hb += 6;
    }
#undef BODY

    // ---- reduction: wave shuffle -> 4-slot LDS -> store/atomic ----
    #pragma unroll
    for (int off = 32; off > 0; off >>= 1) {
        accS += __shfl_down(accS, off, 64);
        accC += __shfl_down(accC, off, 64);
    }
    __shared__ float sS[WPB], sC[WPB];
    if (lane == 0) { sS[wv] = accS; sC[wv] = accC; }
    __syncthreads();
    if (tid == 0) {
        const float ts = sS[0] + sS[1] + sS[2] + sS[3];
        const float tc = sC[0] + sC[1] + sC[2] + sC[3];
        const int bid = blockIdx.y * gridDim.x + blockIdx.x;
        if (direct) {
            accum[2*bid + 0] = ts;
            accum[2*bid + 1] = tc;
        } else {
            const int bin = bid & (NBINS - 1);
            atomicAdd(&accum[2*bin + 0], ts);
            atomicAdd(&accum[2*bin + 1], tc);
        }
    }
}

__global__ __launch_bounds__(256) void finalize_kernel(
    const float* __restrict__ part, int n, float* __restrict__ out)
{
    const int tid = threadIdx.x;
    float s = 0.f, c = 0.f;
    for (int i = tid; i < n; i += 256) {
        s += part[2*i + 0];
        c += part[2*i + 1];
    }
    #pragma unroll
    for (int off = 32; off > 0; off >>= 1) {
        s += __shfl_down(s, off, 64);
        c += __shfl_down(c, off, 64);
    }
    __shared__ float sS[4], sC[4];
    const int wid = tid >> 6, lane = tid & 63;
    if (lane == 0) { sS[wid] = s; sC[wid] = c; }
    __syncthreads();
    if (tid == 0) {
        const float ts = sS[0] + sS[1] + sS[2] + sS[3];
        const float tc = sC[0] + sC[1] + sC[2] + sC[3];
        out[0] = ts / (3.0f * tc);
    }
}

extern "C" void kernel_launch(void* const* d_in, const int* in_sizes, int n_in,
                              void* d_out, int out_size, void* d_ws, size_t ws_size,
                              hipStream_t stream) {
    const float* depth = (const float*)d_in[0];   // [2160][3840] f32
    const float* rgb   = (const float*)d_in[1];   // [2160][3840][3] f32
    const int*   mask  = (const int*)  d_in[2];   // [2160][3840] i32
    const float* lmat  = (const float*)d_in[3];   // [9][3] f32
    const float* K     = (const float*)d_in[4];   // [3][3] f32
    float* accum = (float*)d_ws;
    float* out   = (float*)d_out;

    const dim3 grid(NSX, NSY);                    // 32 x 54 = 1728 blocks x 4 waves

    if (ws_size >= (size_t)NBLOCKS * 2 * sizeof(float)) {
        shading_main<<<grid, 256, 0, stream>>>(depth, rgb, mask, lmat, K, accum, 1);
        finalize_kernel<<<1, 256, 0, stream>>>(accum, NBLOCKS, out);
    } else {
        hipMemsetAsync(accum, 0, NBINS * 2 * sizeof(float), stream);
        shading_main<<<grid, 256, 0, stream>>>(depth, rgb, mask, lmat, K, accum, 0);
        finalize_kernel<<<1, 256, 0, stream>>>(accum, NBINS, out);
    }
}

// Round 7
// 209.761 us; speedup vs baseline: 1.1855x; 1.1855x over previous
//
#include <hip/hip_runtime.h>
#include <math.h>

#define H_IMG 2160
#define W_IMG 3840
#define SPAN 120          // owned cols per strip (sx*SPAN+1 .. sx*SPAN+SPAN; strip 0 also col 0)
#define NSX 32            // 32 * 120 = 3840 exactly; wave covers 128 cols
#define HS 8              // output rows per wave
#define WPB 4             // waves per block: block covers 32 rows
#define NSY 68            // 68 * 32 = 2176 >= 2160 (overhang waves take the guarded path)
#define NBLOCKS (NSX * NSY)   // 2176
#define NBINS 2048

// Lean 2-col/lane kernel: R5 base (48 VGPR, 8-wave regime, 2176 blocks, occ 40%)
// minus per-body overhead. HISTORY: R0/R2/R3/R4/R5 (occ 16-40%, MLP 1-4 deep,
// load-inst count varying 2.6x) ALL land 74-81us; spilled variants sustain
// 2.4TB/s so it's not a BW wall; VALUBusy pinned 29-38%. R5's dynamic stream
// is ~2x the shading math: per-body exec-mask guard churn + 64-bit address
// recompute, paid by EVERY wave though ~1.5% are edge waves. This round:
// (1) wave-uniform edge/interior branch -> interior loop has ZERO guards;
// (2) streaming pointers advanced by stride (no h*W recompute);
// (3) fullIn removed via clamping the last strip's window (wout ownership
// already resolves the overlap). If dur stays ~74us while VALU work drops,
// that's the latency-wall verdict.
// __launch_bounds__ lore: (256,4) = 64-reg budget; R5 fit at 48, this ~52.
__global__ __launch_bounds__(256, 4) void shading_main(
    const float* __restrict__ depth,
    const float* __restrict__ rgb,
    const int*   __restrict__ mask,
    const float* __restrict__ lmat,   // [9][3]
    const float* __restrict__ K,      // [3][3]
    float* __restrict__ accum,        // partial {S,C} pairs
    int direct)
{
    const int tid  = threadIdx.x;
    const int lane = tid & 63;
    const int wv   = tid >> 6;
    const int sx   = blockIdx.x;
    const int x0   = min(sx * SPAN, W_IMG - 128);  // clamp: wave window [x0, x0+127] in-image
    const int y0   = blockIdx.y * (WPB * HS) + wv * HS;
    const int colBase  = x0 + 2 * lane;            // 8B-aligned, always in-image
    const int colBase3 = 3 * colBase;

    // ---- Kinv (adjugate/det; uniform -> SGPRs) ----
    const float m00 = K[0], m01 = K[1], m02 = K[2];
    const float m10 = K[3], m11 = K[4], m12 = K[5];
    const float m20 = K[6], m21 = K[7], m22 = K[8];
    const float det = m00*(m11*m22 - m12*m21)
                    - m01*(m10*m22 - m12*m20)
                    + m02*(m10*m21 - m11*m20);
    const float id  = 1.0f / det;
    const float i00 = (m11*m22 - m12*m21) * id;
    const float i01 = (m02*m21 - m01*m22) * id;
    const float i02 = (m01*m12 - m02*m11) * id;
    const float i10 = (m12*m20 - m10*m22) * id;
    const float i11 = (m00*m22 - m02*m20) * id;
    const float i12 = (m02*m10 - m00*m12) * id;
    const float i20 = (m10*m21 - m11*m20) * id;
    const float i21 = (m01*m20 - m00*m21) * id;
    const float i22 = (m00*m11 - m01*m10) * id;

    float L[27];
    #pragma unroll
    for (int i = 0; i < 27; ++i) L[i] = lmat[i];   // uniform -> s_load

    // ---- output ownership from GLOBAL col (robust to x0 clamp) ----
    float wout[2];
    #pragma unroll
    for (int k = 0; k < 2; ++k) {
        const int c   = colBase + k;
        const int rel = c - sx * SPAN;             // may be <1 on the clamped strip
        const bool v  = (c < W_IMG) && (rel <= SPAN) && (rel >= 1 || sx == 0);
        wout[k] = v ? 1.0f : 0.0f;
    }
    const float qm1s = (lane == 0) ? 0.0f : 1.0f;  // zero only affects unowned/pad cols

    // ---- ray at (colBase, y0-1); +Kinv col1 per row ----
    float rx = fmaf(i00, (float)colBase, fmaf(i01, (float)(y0 - 1), i02));
    float ry = fmaf(i10, (float)colBase, fmaf(i11, (float)(y0 - 1), i12));
    float rz = fmaf(i20, (float)colBase, fmaf(i21, (float)(y0 - 1), i22));

    const float2 Z2 = make_float2(0.f, 0.f);

    // ---- prologue: row y0-1 state + depth row y0 (guarded once) ----
    float2 dC = Z2, dN = Z2;
    float2 raC = Z2, rbC = Z2, rcC = Z2;
    int2   mC  = make_int2(0, 0);
    if (y0 > 0 && (y0 - 1) < H_IMG) {
        const size_t r = (size_t)(y0 - 1);
        dC  = *(const float2*)(depth + r * W_IMG + colBase);
        raC = *(const float2*)(rgb + r * (3 * W_IMG) + colBase3);
        rbC = *(const float2*)(rgb + r * (3 * W_IMG) + colBase3 + 2);
        rcC = *(const float2*)(rgb + r * (3 * W_IMG) + colBase3 + 4);
        mC  = *(const int2*)(mask + r * W_IMG + colBase);
    }
    if (y0 < H_IMG)
        dN = *(const float2*)(depth + (size_t)y0 * W_IMG + colBase);

    // ---- streaming prefetch pointers (advanced by stride; no recompute) ----
    // body j loads depth row y0+1+j, rgb/mask row y0+j
    const float* pfD = depth + (size_t)(y0 + 1) * W_IMG + colBase;
    const float* pfR = rgb   + (size_t)y0 * (3 * W_IMG) + colBase3;
    const int*   pfM = mask  + (size_t)y0 * W_IMG + colBase;

    // rolling state (constant indices only; becomes loop-carried phis)
    float sA0[2] = {0,0}, sA1[2] = {0,0}, sA2[2] = {0,0};
    float sB0[2] = {0,0}, sB1[2] = {0,0}, sB2[2] = {0,0};
    float qB0[2] = {0,0}, qB1[2] = {0,0}, qB2[2] = {0,0};
    float wB[2]  = {0,0};
    float accS = 0.f, accC = 0.f;

// The row loop, parameterized on GUARD (compile-time 0/1). Interior waves
// (GUARD=0) run straight-line loads: no exec-mask churn, no zero-fills.
#define MAINLOOP(GUARD)                                                        \
    _Pragma("unroll 1")                                                        \
    for (int j = 0; j < HS + 2; ++j) {                                         \
        float2 dP, raN, rbN, rcN; int2 mN;                                     \
        if (GUARD) {                                                           \
            dP = Z2; raN = Z2; rbN = Z2; rcN = Z2; mN = make_int2(0, 0);       \
            if (y0 + 1 + j < H_IMG) dP = *(const float2*)pfD;                  \
            if (y0 + j < H_IMG) {                                              \
                raN = *(const float2*)(pfR);                                   \
                rbN = *(const float2*)(pfR + 2);                               \
                rcN = *(const float2*)(pfR + 4);                               \
                mN  = *(const int2*)(pfM);                                     \
            }                                                                  \
        } else {                                                               \
            dP  = *(const float2*)pfD;                                         \
            raN = *(const float2*)(pfR);                                       \
            rbN = *(const float2*)(pfR + 2);                                   \
            rcN = *(const float2*)(pfR + 4);                                   \
            mN  = *(const int2*)(pfM);                                         \
        }                                                                      \
        pfD += W_IMG; pfR += 3 * W_IMG; pfM += W_IMG;                          \
                                                                               \
        const float dcv[2] = {dC.x, dC.y};                                     \
        const float dnv[2] = {dN.x, dN.y};                                     \
        const float rrv[6] = {raC.x, raC.y, rbC.x, rbC.y, rcC.x, rcC.y};       \
        const int   mmv[2] = {mC.x, mC.y};                                     \
        const float dcR = __shfl_down(dC.x, 1, 64);                            \
                                                                               \
        float qC0[2], qC1[2], qC2[2], wC[2];                                   \
        float rxk = rx, ryk = ry, rzk = rz;                                    \
        _Pragma("unroll")                                                      \
        for (int k = 0; k < 2; ++k) {                                          \
            const float d0 = dcv[k];                                           \
            const float dR = (k == 0) ? dcv[1] : dcR;                          \
            const float dD = dnv[k];                                           \
            const float px = rxk * d0, py = ryk * d0, pz = rzk * d0;           \
            const float ax = (rxk + i00) * dR - px;                            \
            const float ay = (ryk + i10) * dR - py;                            \
            const float az = (rzk + i20) * dR - pz;                            \
            const float bx = (rxk + i01) * dD - px;                            \
            const float by = (ryk + i11) * dD - py;                            \
            const float bz = (rzk + i21) * dD - pz;                            \
            float nx = ay*bz - az*by;                                          \
            float ny = az*bx - ax*bz;                                          \
            float nz = ax*by - ay*bx;                                          \
            const float nn  = nx*nx + ny*ny + nz*nz;                           \
            const float inr = __builtin_amdgcn_rsqf(fmaxf(nn, 1e-24f));        \
            nx *= inr; ny *= inr; nz *= inr;                                   \
            const float h4 = nx*ny, h5 = ny*nz, h7 = nz*nx;                    \
            const float nx2 = nx*nx, ny2 = ny*ny, nz2 = nz*nz;                 \
            const float h6 = 2.f*nz2 - nx2 - ny2;                              \
            const float h8 = nx2 - ny2;                                        \
            const float B0 = L[0] + ny*L[3] + nz*L[6] + nx*L[9]  + h4*L[12]    \
                           + h5*L[15] + h6*L[18] + h7*L[21] + h8*L[24];        \
            const float B1 = L[1] + ny*L[4] + nz*L[7] + nx*L[10] + h4*L[13]    \
                           + h5*L[16] + h6*L[19] + h7*L[22] + h8*L[25];        \
            const float B2 = L[2] + ny*L[5] + nz*L[8] + nx*L[11] + h4*L[14]    \
                           + h5*L[17] + h6*L[20] + h7*L[23] + h8*L[26];        \
            const float m  = (mmv[k] > 0) ? 1.0f : 0.0f;                       \
            qC0[k] = fmaf(m, B0, -rrv[3*k + 0]);                               \
            qC1[k] = fmaf(m, B1, -rrv[3*k + 1]);                               \
            qC2[k] = fmaf(m, B2, -rrv[3*k + 2]);                               \
            wC[k]  = m * wout[k];                                              \
            rxk += i00; ryk += i10; rzk += i20;                                \
        }                                                                      \
                                                                               \
        float sC0[2], sC1[2], sC2[2];                                          \
        {                                                                      \
            const float a0 = __shfl_up(qC0[1], 1, 64) * qm1s;                  \
            const float a1 = __shfl_up(qC1[1], 1, 64) * qm1s;                  \
            const float a2 = __shfl_up(qC2[1], 1, 64) * qm1s;                  \
            const float p0 = __shfl_down(qC0[0], 1, 64);                       \
            const float p1 = __shfl_down(qC1[0], 1, 64);                       \
            const float p2 = __shfl_down(qC2[0], 1, 64);                       \
            const float t0 = qC0[0] + qC0[1];                                  \
            sC0[0] = a0 + t0;  sC0[1] = t0 + p0;                               \
            const float t1 = qC1[0] + qC1[1];                                  \
            sC1[0] = a1 + t1;  sC1[1] = t1 + p1;                               \
            const float t2 = qC2[0] + qC2[1];                                  \
            sC2[0] = a2 + t2;  sC2[1] = t2 + p2;                               \
        }                                                                      \
                                                                               \
        if (j >= 2) {                                                          \
            _Pragma("unroll")                                                  \
            for (int k = 0; k < 2; ++k) {                                      \
                const float v0 = sA0[k] + sB0[k] + sC0[k];                     \
                const float v1 = sA1[k] + sB1[k] + sC1[k];                     \
                const float v2 = sA2[k] + sB2[k] + sC2[k];                     \
                const float e0 = fmaf(v0, -(1.f/9.f), qB0[k]);                 \
                const float e1 = fmaf(v1, -(1.f/9.f), qB1[k]);                 \
                const float e2 = fmaf(v2, -(1.f/9.f), qB2[k]);                 \
                const float w  = wB[k];                                        \
                accS = fmaf(w, e0*e0 + e1*e1 + e2*e2, accS);                   \
                accC += w;                                                     \
            }                                                                  \
        }                                                                      \
                                                                               \
        _Pragma("unroll")                                                      \
        for (int k = 0; k < 2; ++k) {                                          \
            sA0[k] = sB0[k]; sA1[k] = sB1[k]; sA2[k] = sB2[k];                 \
            sB0[k] = sC0[k]; sB1[k] = sC1[k]; sB2[k] = sC2[k];                 \
            qB0[k] = qC0[k]; qB1[k] = qC1[k]; qB2[k] = qC2[k];                 \
            wB[k]  = wC[k];                                                    \
        }                                                                      \
        dC = dN; dN = dP;                                                      \
        raC = raN; rbC = rbN; rcC = rcN; mC = mN;                              \
        rx += i01; ry += i11; rz += i21;                                       \
    }

    // interior iff no loaded row can exceed the image: depth rows reach y0+HS+2
    const bool edge = (y0 == 0) || (y0 + HS + 2 > H_IMG - 1);
    if (edge) {
        MAINLOOP(1)
    } else {
        MAINLOOP(0)
    }
#undef MAINLOOP

    // ---- reduction: wave shuffle -> 4-slot LDS -> store/atomic ----
    #pragma unroll
    for (int off = 32; off > 0; off >>= 1) {
        accS += __shfl_down(accS, off, 64);
        accC += __shfl_down(accC, off, 64);
    }
    __shared__ float sS[WPB], sC[WPB];
    if (lane == 0) { sS[wv] = accS; sC[wv] = accC; }
    __syncthreads();
    if (tid == 0) {
        const float ts = sS[0] + sS[1] + sS[2] + sS[3];
        const float tc = sC[0] + sC[1] + sC[2] + sC[3];
        const int bid = blockIdx.y * gridDim.x + blockIdx.x;
        if (direct) {
            accum[2*bid + 0] = ts;
            accum[2*bid + 1] = tc;
        } else {
            const int bin = bid & (NBINS - 1);
            atomicAdd(&accum[2*bin + 0], ts);
            atomicAdd(&accum[2*bin + 1], tc);
        }
    }
}

__global__ __launch_bounds__(256) void finalize_kernel(
    const float* __restrict__ part, int n, float* __restrict__ out)
{
    const int tid = threadIdx.x;
    float s = 0.f, c = 0.f;
    for (int i = tid; i < n; i += 256) {
        s += part[2*i + 0];
        c += part[2*i + 1];
    }
    #pragma unroll
    for (int off = 32; off > 0; off >>= 1) {
        s += __shfl_down(s, off, 64);
        c += __shfl_down(c, off, 64);
    }
    __shared__ float sS[4], sC[4];
    const int wid = tid >> 6, lane = tid & 63;
    if (lane == 0) { sS[wid] = s; sC[wid] = c; }
    __syncthreads();
    if (tid == 0) {
        const float ts = sS[0] + sS[1] + sS[2] + sS[3];
        const float tc = sC[0] + sC[1] + sC[2] + sC[3];
        out[0] = ts / (3.0f * tc);
    }
}

extern "C" void kernel_launch(void* const* d_in, const int* in_sizes, int n_in,
                              void* d_out, int out_size, void* d_ws, size_t ws_size,
                              hipStream_t stream) {
    const float* depth = (const float*)d_in[0];   // [2160][3840] f32
    const float* rgb   = (const float*)d_in[1];   // [2160][3840][3] f32
    const int*   mask  = (const int*)  d_in[2];   // [2160][3840] i32
    const float* lmat  = (const float*)d_in[3];   // [9][3] f32
    const float* K     = (const float*)d_in[4];   // [3][3] f32
    float* accum = (float*)d_ws;
    float* out   = (float*)d_out;

    const dim3 grid(NSX, NSY);                    // 32 x 68 = 2176 blocks x 4 waves

    if (ws_size >= (size_t)NBLOCKS * 2 * sizeof(float)) {
        shading_main<<<grid, 256, 0, stream>>>(depth, rgb, mask, lmat, K, accum, 1);
        finalize_kernel<<<1, 256, 0, stream>>>(accum, NBLOCKS, out);
    } else {
        hipMemsetAsync(accum, 0, NBINS * 2 * sizeof(float), stream);
        shading_main<<<grid, 256, 0, stream>>>(depth, rgb, mask, lmat, K, accum, 0);
        finalize_kernel<<<1, 256, 0, stream>>>(accum, NBINS, out);
    }
}